// Round 4
// baseline (1074.832 us; speedup 1.0000x reference)
//
#include <hip/hip_runtime.h>
#include <cmath>

typedef float f4_t __attribute__((ext_vector_type(4)));
typedef float f2_t __attribute__((ext_vector_type(2)));
typedef long  l2_t __attribute__((ext_vector_type(2)));

#define B_TOTAL   65536
#define FTW_SCALE 1024.0f
#define INV_SCALE (1.0f/1024.0f)
#define L1WT_OFF  (768 * 1024)

__device__ __forceinline__ int pk8(float a, float b, float c, float d) {
    int v = __builtin_amdgcn_cvt_pk_fp8_f32(a, b, 0, false);
    return  __builtin_amdgcn_cvt_pk_fp8_f32(c, d, v, true);
}
__device__ __forceinline__ float clip01(float x) { return fminf(fmaxf(x, 0.f), 1.f); }

// ---------------------------------------------------------------------------
// Pack ft_w [1024][768] fp32 -> fp8(e4m3, x1024) in frag-pair order:
//   ws[(kk*32 + ncp)*1024 + lane*16]  holds cols ncp*32+[0,32) for k-chunk kk
//   bytes 0-7 = cols +[0,16) frag, bytes 8-15 = cols +[16,32) frag.
// ---------------------------------------------------------------------------
__global__ void pack_ftw_kernel(const float* __restrict__ ftw, char* __restrict__ ws)
{
    int t    = blockIdx.x * 256 + threadIdx.x;   // 0..49151
    int lane = t & 63;
    int ncp  = (t >> 6) & 31;
    int kk   = t >> 11;                          // 0..23
    int nl = lane & 15, q = (lane >> 4) & 3;
    int k0 = kk * 32 + q * 8;
    const float* p0 = ftw + (size_t)(ncp * 32 + nl) * 768 + k0;
    const float* p1 = p0 + 16 * 768;
    float4 x0 = *(const float4*)p0;
    float4 x1 = *(const float4*)(p0 + 4);
    float4 y0 = *(const float4*)p1;
    float4 y1 = *(const float4*)(p1 + 4);
    int4 o;
    o.x = pk8(x0.x*FTW_SCALE, x0.y*FTW_SCALE, x0.z*FTW_SCALE, x0.w*FTW_SCALE);
    o.y = pk8(x1.x*FTW_SCALE, x1.y*FTW_SCALE, x1.z*FTW_SCALE, x1.w*FTW_SCALE);
    o.z = pk8(y0.x*FTW_SCALE, y0.y*FTW_SCALE, y0.z*FTW_SCALE, y0.w*FTW_SCALE);
    o.w = pk8(y1.x*FTW_SCALE, y1.y*FTW_SCALE, y1.z*FTW_SCALE, y1.w*FTW_SCALE);
    *(int4*)(ws + (size_t)t * 16) = o;
}

// ---------------------------------------------------------------------------
// Transpose l1_w [8][2048] -> l1wT [2048][8]: one column's 8 output-weights
// become contiguous (vector-loadable) instead of 16 stride-8KB scalars.
// ---------------------------------------------------------------------------
__global__ void pack_l1w_kernel(const float* __restrict__ l1w, float* __restrict__ l1wT)
{
    int t = blockIdx.x * 256 + threadIdx.x;   // 0..16383
    int c = t >> 3, o = t & 7;
    l1wT[t] = l1w[o * 2048 + c];
}

// 8 MFMAs of one k-chunk: 2 m-tiles (w,b) x 2 n-frags against one B reg pair
#define STEP8(AW, AB, BV)                                                                   \
    acc[0][0] = __builtin_amdgcn_mfma_f32_16x16x32_fp8_fp8((AW), (BV).x, acc[0][0], 0,0,0); \
    acc[1][0] = __builtin_amdgcn_mfma_f32_16x16x32_fp8_fp8((AB), (BV).x, acc[1][0], 0,0,0); \
    acc[0][1] = __builtin_amdgcn_mfma_f32_16x16x32_fp8_fp8((AW), (BV).y, acc[0][1], 0,0,0); \
    acc[1][1] = __builtin_amdgcn_mfma_f32_16x16x32_fp8_fp8((AB), (BV).y, acc[1][1], 0,0,0);

// ---------------------------------------------------------------------------
// Fused kernel, Round 4: 16 samples/block (4096 blocks).
// Rationale: the backend pins the register budget at the 6-wave tier (~84)
// regardless of attributes (R1-R3: every extra live range spilled, WRITE_SIZE
// 336-484 MB). But LDS at 52 KB allowed only 3 blocks/CU = 3 waves/EU. Halve
// the block: LDS 26 KB -> 6 blocks/CU = 24 waves/CU (matches the 6-wave
// register tier), and per-wave state (pacc 64->32, acc 32->16) fits the cap
// WITH a depth-2 rolling B prefetch (issue-to-use ~200cy >= L2 hit latency).
//   LDS A layout: Ald[(kk*2+p)*512 + slot*8], slot: row=slot&15, koct=slot>>4
//   holds A[row][kk*32+koct*8 ..+8] as 8 fp8 — the exact MFMA A fragment.
// ---------------------------------------------------------------------------
__global__ __launch_bounds__(256, 6) void nnue_fused_kernel(
    const float* __restrict__ wf,  const float* __restrict__ bfeat,
    const float* __restrict__ stm, const char*  __restrict__ ftw8,
    const float* __restrict__ ftb, const float* __restrict__ l1wT,
    const float* __restrict__ l1b, const float* __restrict__ l2w,
    const float* __restrict__ l2b, const float* __restrict__ l3w,
    const float* __restrict__ l3b, float* __restrict__ out)
{
    __shared__ char  Ald[48 * 512];       // 24 KB
    __shared__ float l1part[4][16][8];    // 2 KB

    const int t    = threadIdx.x;
    const int lane = t & 63;
    const int wave = t >> 6;
    const int nl   = lane & 15;
    const int q    = (lane >> 4) & 3;
    const int s0   = blockIdx.x * 16;

    // ---- stage A: fp32 -> fp8 directly into fragment layout ----
    // 48 chunks (kk 0..23 x p{w,b}) of 512 B; thread t covers slot t&63 of
    // chunks (t>>6)*12 .. +11.
    {
        const int sl  = t & 63;
        const int g   = t >> 6;
        const int row = sl & 15, ko = sl >> 4;
        const float* wr = wf    + (size_t)(s0 + row) * 768 + ko * 8;
        const float* br = bfeat + (size_t)(s0 + row) * 768 + ko * 8;
        char* dst = &Ald[sl * 8];
        #pragma unroll 4
        for (int pass = 0; pass < 12; ++pass) {
            int c  = g * 12 + pass;      // chunk 0..47
            int kk = c >> 1, p = c & 1;
            const float* src = (p ? br : wr) + kk * 32;
            float4 x0 = *(const float4*)src;
            float4 x1 = *(const float4*)(src + 4);
            int2 o;
            o.x = pk8(x0.x, x0.y, x0.z, x0.w);
            o.y = pk8(x1.x, x1.y, x1.z, x1.w);
            *(int2*)(dst + c * 512) = o;
        }
    }

    float s_r[4];
    #pragma unroll
    for (int r = 0; r < 4; ++r) s_r[r] = stm[s0 + q * 4 + r];

    __syncthreads();

    f2_t pacc[4][4];                      // l1 partials [r][o-pair]
    #pragma unroll
    for (int r = 0; r < 4; ++r)
        #pragma unroll
        for (int i = 0; i < 4; ++i) pacc[r][i] = (f2_t){0.f, 0.f};

    const char* ap8 = &Ald[lane * 8];
    const char* bpw = ftw8 + (size_t)(wave * 8) * 1024 + (size_t)lane * 16;

    #pragma unroll 1
    for (int ng = 0; ng < 8; ++ng) {
        const char* bp = bpw + ng * 1024;

        // reseed the rolling depth-2 B pipeline (chunks 0..3); nothing from
        // the pipeline is live across the epilogue below.
        l2_t bc0 = *(const l2_t*)(bp);
        l2_t bc1 = *(const l2_t*)(bp + 1 * 32768);
        l2_t bm0 = *(const l2_t*)(bp + 2 * 32768);
        l2_t bm1 = *(const l2_t*)(bp + 3 * 32768);

        f4_t acc[2][2];
        acc[0][0] = (f4_t){0.f,0.f,0.f,0.f};
        acc[0][1] = (f4_t){0.f,0.f,0.f,0.f};
        acc[1][0] = (f4_t){0.f,0.f,0.f,0.f};
        acc[1][1] = (f4_t){0.f,0.f,0.f,0.f};

        #pragma unroll
        for (int kg = 0; kg < 12; ++kg) {
            // prefetch chunks 2kg+4, 2kg+5 (2-iter distance ~200cy >= L2 hit)
            l2_t bn0, bn1;
            if (kg < 10) {
                bn0 = *(const l2_t*)(bp + (2 * kg + 4) * 32768);
                bn1 = *(const l2_t*)(bp + (2 * kg + 5) * 32768);
            }

            long aw  = *(const long*)(ap8 + (4 * kg    ) * 512);
            long ab  = *(const long*)(ap8 + (4 * kg + 1) * 512);
            STEP8(aw, ab, bc0)
            long aw2 = *(const long*)(ap8 + (4 * kg + 2) * 512);
            long ab2 = *(const long*)(ap8 + (4 * kg + 3) * 512);
            STEP8(aw2, ab2, bc1)

            bc0 = bm0; bc1 = bm1;
            if (kg < 10) { bm0 = bn0; bm1 = bn1; }
        }

        // epilogue: blend + clip + l1 partial dot over this ng's 32 columns
        #pragma unroll
        for (int nb = 0; nb < 2; ++nb) {
            const int col = wave * 256 + ng * 32 + nb * 16 + nl;
            float bias = ftb[col];
            const float* wl = l1wT + (size_t)col * 8;
            f2_t L0 = *(const f2_t*)(wl);
            f2_t L1 = *(const f2_t*)(wl + 2);
            f2_t L2 = *(const f2_t*)(wl + 4);
            f2_t L3 = *(const f2_t*)(wl + 6);
            f2_t H0 = *(const f2_t*)(wl + 8192);      // col+1024
            f2_t H1 = *(const f2_t*)(wl + 8192 + 2);
            f2_t H2 = *(const f2_t*)(wl + 8192 + 4);
            f2_t H3 = *(const f2_t*)(wl + 8192 + 6);
            #pragma unroll
            for (int r = 0; r < 4; ++r) {
                float w0 = fmaf(acc[0][nb][r], INV_SCALE, bias);
                float b0 = fmaf(acc[1][nb][r], INV_SCALE, bias);
                float d0 = w0 - b0;
                float f0 = clip01(fmaf( s_r[r], d0, b0));   // stm*w + (1-stm)*b
                float g0 = clip01(fmaf(-s_r[r], d0, w0));   // stm*b + (1-stm)*w
                pacc[r][0] += f0 * L0 + g0 * H0;
                pacc[r][1] += f0 * L1 + g0 * H1;
                pacc[r][2] += f0 * L2 + g0 * H2;
                pacc[r][3] += f0 * L3 + g0 * H3;
            }
        }
    }

    // reduce partials across the 16 column-lanes
    #pragma unroll
    for (int m = 1; m < 16; m <<= 1)
        #pragma unroll
        for (int r = 0; r < 4; ++r)
            #pragma unroll
            for (int i = 0; i < 4; ++i) {
                pacc[r][i].x += __shfl_xor(pacc[r][i].x, m);
                pacc[r][i].y += __shfl_xor(pacc[r][i].y, m);
            }

    if (nl == 0) {
        #pragma unroll
        for (int r = 0; r < 4; ++r)
            #pragma unroll
            for (int i = 0; i < 4; ++i) {
                l1part[wave][q * 4 + r][2*i]   = pacc[r][i].x;
                l1part[wave][q * 4 + r][2*i+1] = pacc[r][i].y;
            }
    }
    __syncthreads();

    // tail MLP: l1 bias+clip -> l2 -> l3 -> sigmoid
    if (t < 16) {
        float v[8];
        #pragma unroll
        for (int o = 0; o < 8; ++o)
            v[o] = clip01(l1part[0][t][o] + l1part[1][t][o] +
                          l1part[2][t][o] + l1part[3][t][o] + l1b[o]);
        float raw = l3b[0];
        #pragma unroll
        for (int u = 0; u < 32; ++u) {
            float h = l2b[u];
            #pragma unroll
            for (int o = 0; o < 8; ++o) h = fmaf(v[o], l2w[u * 8 + o], h);
            h = clip01(h);
            raw = fmaf(h, l3w[u], raw);
        }
        out[s0 + t]           = 1.0f / (1.0f + expf(-raw));
        out[B_TOTAL + s0 + t] = raw;
    }
}

extern "C" void kernel_launch(void* const* d_in, const int* in_sizes, int n_in,
                              void* d_out, int out_size, void* d_ws, size_t ws_size,
                              hipStream_t stream)
{
    (void)in_sizes; (void)n_in; (void)out_size; (void)ws_size;
    const float* wf  = (const float*)d_in[0];
    const float* bf  = (const float*)d_in[1];
    const float* stm = (const float*)d_in[2];
    const float* ftw = (const float*)d_in[3];
    const float* ftb = (const float*)d_in[4];
    const float* l1w = (const float*)d_in[5];
    const float* l1b = (const float*)d_in[6];
    const float* l2w = (const float*)d_in[7];
    const float* l2b = (const float*)d_in[8];
    const float* l3w = (const float*)d_in[9];
    const float* l3b = (const float*)d_in[10];
    char*  ws8  = (char*)d_ws;                      // 768 KB packed fp8 ft_w
    float* l1wT = (float*)(ws8 + L1WT_OFF);         // 64 KB transposed l1w

    hipLaunchKernelGGL(pack_ftw_kernel, dim3(192), dim3(256), 0, stream, ftw, ws8);
    hipLaunchKernelGGL(pack_l1w_kernel, dim3(64), dim3(256), 0, stream, l1w, l1wT);
    hipLaunchKernelGGL(nnue_fused_kernel, dim3(4096), dim3(256), 0, stream,
                       wf, bf, stm, ws8, ftb, l1wT, l1b, l2w, l2b, l3w, l3b,
                       (float*)d_out);
}